// Round 16
// baseline (209.644 us; speedup 1.0000x reference)
//
#include <hip/hip_runtime.h>
#include <hip/hip_bf16.h>
#include <stdint.h>

typedef __bf16 bf16;
typedef __bf16 bf16x4 __attribute__((ext_vector_type(4)));
typedef __bf16 bf16x8 __attribute__((ext_vector_type(8)));
typedef float f32x4 __attribute__((ext_vector_type(4)));
typedef float f32x16 __attribute__((ext_vector_type(16)));

#define GLDS16(g, l) __builtin_amdgcn_global_load_lds( \
    (const __attribute__((address_space(1))) void*)(g), \
    (__attribute__((address_space(3))) void*)(l), 16, 0, 0)

static constexpr int S = 2048;

// ---- fused f32->bf16 convert (x + 4 weights) + RoPE cos/sin table build ----
__global__ __launch_bounds__(256) void cvt_all(const float* __restrict__ x,
                                               const float* __restrict__ wq,
                                               const float* __restrict__ wk,
                                               const float* __restrict__ wv,
                                               const float* __restrict__ wo,
                                               const int* __restrict__ tp,
                                               bf16* __restrict__ xb,
                                               bf16* __restrict__ wqkvb,
                                               bf16* __restrict__ wob,
                                               bf16* __restrict__ tabc,
                                               bf16* __restrict__ tabs) {
  const int bid = blockIdx.x;
  if (bid >= 6144) {   // RoPE table: 8192 rows x 32 pairs
    int idx = (bid - 6144) * 256 + threadIdx.x;   // 0..262143
    int row = idx >> 5, pp = idx & 31;
    float p = (float)tp[row];
    float ang = p * exp2f((float)pp * -0.4152410118609203f);
    float sn, cs;
    sincosf(ang, &sn, &cs);
    tabc[idx] = (bf16)cs;
    tabs[idx] = (bf16)sn;
    return;
  }
  const float* src;
  bf16* dst;
  int i;
  if (bid < 4096) {            // x: 1,048,576 groups of 8
    src = x; dst = xb; i = bid * 256 + threadIdx.x;
  } else {                     // weights: 131,072 groups each
    int w = (bid - 4096) >> 9;
    i = ((bid - 4096) & 511) * 256 + threadIdx.x;
    src = (w == 0) ? wq : (w == 1) ? wk : (w == 2) ? wv : wo;
    dst = (w == 3) ? wob : wqkvb + (size_t)w * 1048576;
  }
  const float4* p = (const float4*)src + (size_t)i * 2;
  float4 a = p[0], b = p[1];
  bf16x8 o;
  o[0] = (bf16)a.x; o[1] = (bf16)a.y; o[2] = (bf16)a.z; o[3] = (bf16)a.w;
  o[4] = (bf16)b.x; o[5] = (bf16)b.y; o[6] = (bf16)b.z; o[7] = (bf16)b.w;
  *((bf16x8*)dst + i) = o;
}

// ------- NT GEMM, 128x128, BK=32: A via LDS (dbuf, 1 barrier), B direct -----
// LDS-BW theory: the ~870 TF band = LDS port moving 48 KB/block-step. Fix:
// B-fragments load straight from global (L2-resident weight panels) into
// statically double-buffered registers bgA/bgB -> LDS traffic halves to
// 24 KB/block-step (A-stage 8 + A-read 16). A: 2-buffer ring, stage(t+1)
// issued AFTER barrier t (WAR: b[(t+1)%2] was read at t-1; those reads are
// lgkm-complete before each wave passes barrier t). vmcnt(0) at step top is
// exact: only {A(t):2, B(t):4} in flight, issued a full step (~2400cyc) ago.
// chunk^((row>>1)&3) swizzle pre-applied to A's global source. 2D grid
// natural dispatch: XCD = bm%8 -> blocks sharing panels co-locate on L2.
// MODE 0 (QKV, grid 64x24): bn<8 q, bn<16 k (table-RoPE, LDS-bounce stores);
//   bn>=16 v = W.x^T -> [b,h,dd,s] coalesced rows.
// MODE 2 (wo, grid 64x8): f32 direct stores to [m][1024].
template <int MODE>
__global__ __launch_bounds__(256, 3) void gemm_k(const bf16* __restrict__ xA,
                                                 const bf16* __restrict__ wB,
                                                 const bf16* __restrict__ tabc,
                                                 const bf16* __restrict__ tabs,
                                                 bf16* __restrict__ oq,
                                                 bf16* __restrict__ ok,
                                                 bf16* __restrict__ ov,
                                                 float* __restrict__ outf) {
  constexpr int K = 1024;
  __shared__ __align__(16) char lds[17408];   // A-ring 2x8KB; epilogue overlay
  const int t = threadIdx.x, l = t & 63, wid = t >> 6;
  const int wm = wid >> 1, wn = wid & 1;
  const int bm = blockIdx.x, bn = blockIdx.y;

  // ---- block decode
  int sel, tA, tB;
  const bf16 *Ap, *Bp;
  if (MODE == 0) {
    if (bn < 16) {
      sel = bn >> 3;                                 // 0=q, 1=k
      tA = bm;                                       // s-tile 0..63
      tB = bn & 7;                                   // col-tile 0..7
      Ap = xA + (size_t)tA * 128 * K;
      Bp = wB + (size_t)(sel * 1024 + tB * 128) * K;
    } else {
      sel = 2;
      tA = bn - 16;                                  // dd-tile 0..7
      tB = bm;                                       // s-tile 0..63
      Ap = wB + (size_t)(2048 + tA * 128) * K;       // A = wv rows (dd)
      Bp = xA + (size_t)tB * 128 * K;                // B = x rows (s)
    }
  } else {
    sel = 3;
    tA = bm; tB = bn;
    Ap = xA + (size_t)tA * 128 * K;
    Bp = wB + (size_t)tB * 128 * K;
  }

  // ---- A staging: 2 GLDS16/wave/step; lane l -> row l>>2, chunk l&3 (16B)
  const int lrow = l >> 2;
  const int csrc = ((l & 3) ^ ((l >> 3) & 3)) * 8;
  const bf16* aS = Ap + (size_t)(wid * 32 + lrow) * K + csrc;

  auto stage = [&](int kt, char* base) {
    GLDS16(aS + kt, base + (wid * 32) * 64);
    GLDS16(aS + (size_t)16 * K + kt, base + (wid * 32 + 16) * 64);
  };

  // ---- A fragment LDS read offsets (loop-invariant)
  int offA[4];
#pragma unroll
  for (int f = 0; f < 4; f++) {
    int ra = wm * 64 + f * 16 + (l & 15);
    offA[f] = ra * 64 + (((l >> 4) ^ ((ra >> 1) & 3)) * 16);
  }

  // ---- B fragment global pointers (per-lane; 16B each, 64B/row coalesced)
  const bf16* bp[4];
#pragma unroll
  for (int f = 0; f < 4; f++)
    bp[f] = Bp + (size_t)(wn * 64 + f * 16 + (l & 15)) * K + (l >> 4) * 8;

  f32x4 acc[4][4] = {};
  bf16x8 bgA[4], bgB[4];

  char* b0 = lds;
  char* b1 = lds + 8192;

  // prologue: A(0) -> b0; B(0) -> bgA
  stage(0, b0);
#pragma unroll
  for (int f = 0; f < 4; f++) bgA[f] = *(const bf16x8*)(bp[f]);

  auto kbody = [&](const char* curb, char* stb, int knext,
                   bf16x8 (&bgu)[4], bf16x8 (&bgl)[4]) {
    asm volatile("s_waitcnt vmcnt(0)" ::: "memory");
    __builtin_amdgcn_s_barrier();
    __builtin_amdgcn_sched_barrier(0);
    if (knext < K) stage(knext, stb);     // A(t+1) into buffer read at t-1
    bf16x8 af[4];
#pragma unroll
    for (int f = 0; f < 4; f++) af[f] = *(const bf16x8*)(curb + offA[f]);
    if (knext < K) {
#pragma unroll
      for (int f = 0; f < 4; f++) bgl[f] = *(const bf16x8*)(bp[f] + knext);
    }
    __builtin_amdgcn_s_setprio(1);
#pragma unroll
    for (int mi = 0; mi < 4; mi++)
#pragma unroll
      for (int ni = 0; ni < 4; ni++)
        acc[mi][ni] = __builtin_amdgcn_mfma_f32_16x16x32_bf16(
            af[mi], bgu[ni], acc[mi][ni], 0, 0, 0);
    __builtin_amdgcn_s_setprio(0);
  };

#pragma unroll 1
  for (int t2 = 0; t2 < 16; ++t2) {
    kbody(b0, b1, (2 * t2 + 1) * 32, bgA, bgB);
    kbody(b1, b0, (2 * t2 + 2) * 32, bgB, bgA);
  }

  if (MODE == 2) {   // wo: direct f32 stores (64 B segments, full lines)
    const int rbase = tA * 128 + wm * 64 + (l >> 4) * 4;
    const int cbase = tB * 128 + wn * 64 + (l & 15);
#pragma unroll
    for (int mi = 0; mi < 4; mi++)
#pragma unroll
      for (int ni = 0; ni < 4; ni++)
#pragma unroll
        for (int r = 0; r < 4; r++)
          outf[(size_t)(rbase + mi * 16 + r) * 1024 + cbase + ni * 16] =
              acc[mi][ni][r];
    return;
  }

  // ---- 2-pass half-tile epilogue via 64x272B overlay (ring is dead)
  __syncthreads();
#pragma unroll 1
  for (int pass = 0; pass < 2; ++pass) {
    if (wm == pass) {   // waves owning rows [pass*64, pass*64+64)
#pragma unroll
      for (int mi = 0; mi < 4; mi++)
#pragma unroll
        for (int ni = 0; ni < 4; ni++)
#pragma unroll
          for (int r = 0; r < 4; r++) {
            int rloc = mi * 16 + (l >> 4) * 4 + r;       // 0..63
            int col = wn * 64 + ni * 16 + (l & 15);      // 0..127
            *(bf16*)(lds + rloc * 272 + col * 2) = (bf16)acc[mi][ni][r];
          }
    }
    __syncthreads();
#pragma unroll 2
    for (int i = 0; i < 4; ++i) {
      const int id = t + 256 * i;
      const int rloc = id >> 4, ch = id & 15;
      bf16x8 v8 = *(const bf16x8*)(lds + rloc * 272 + ch * 16);
      const int row = pass * 64 + rloc;
      if (sel < 2) {
        const int m = tA * 128 + row;
        const int g = ch & 7;
        bf16x4 tc = *(const bf16x4*)(tabc + m * 32 + g * 4);
        bf16x4 tsn = *(const bf16x4*)(tabs + m * 32 + g * 4);
        bf16x8 o;
#pragma unroll
        for (int j = 0; j < 4; j++) {
          float cs = (float)tc[j], sn = (float)tsn[j];
          float e = (float)v8[2 * j], od = (float)v8[2 * j + 1];
          o[2 * j]     = (bf16)(e * cs - od * sn);
          o[2 * j + 1] = (bf16)(e * sn + od * cs);
        }
        bf16* dst = (sel == 0) ? oq : ok;
        const int h = tB * 2 + (ch >> 3);
        size_t idx = ((size_t)((m >> 11) * 16 + h) << 17) +
                     ((size_t)(m & 2047) << 6) + g * 8;
        *(bf16x8*)(dst + idx) = o;
      } else {
        const int dd = tA * 128 + row;
        const int h = dd >> 6;
        const int s0 = tB * 128 + ch * 8;
        size_t idx = ((size_t)((s0 >> 11) * 16 + h) << 17) +
                     ((size_t)(dd & 63) << 11) + (s0 & 2047);
        *(bf16x8*)(ov + idx) = v8;
      }
    }
    __syncthreads();
  }
}

// ---------------- causal flash attention, KVBLK=128 per barrier-pair --------
// (r12-proven) 512 blocks (one (bh,qt) each), 8 waves, QBLK=256. Each step
// stages TWO 64-kv sub-tiles; barriers per kv halved. Double-buffered (64 KB),
// counted vmcnt(4), 2 blocks/CU. Swapped QK^T; sigma-permuted in-register P;
// no max-subtract softmax.
__global__ __launch_bounds__(512, 4) void attn_k(const bf16* __restrict__ q,
                                                 const bf16* __restrict__ k,
                                                 const bf16* __restrict__ vt,
                                                 bf16* __restrict__ att) {
  __shared__ bf16 Ks[2][8192];   // [buf][sub*4096 + kv64 x d64], swizzled
  __shared__ bf16 Vs[2][8192];   // [buf][sub*4096 + d64 x kv64], swizzled

  const int t = threadIdx.x, l = t & 63, w = t >> 6;   // w = 0..7
  const int hi2 = l >> 5, q5 = l & 31;

  const int raw = blockIdx.x;
  const int r2 = raw & 255;
  const int wg = (r2 & 7) * 32 + (r2 >> 3);      // 4 bh per XCD, L2-local
  const int bh = ((raw < 256) ? 0 : 32) + (wg >> 3);
  const int qt = (raw < 256) ? (wg & 7) : 7 - (wg & 7);

  const bf16* qb = q + (size_t)bh * S * 64;
  const bf16* kb = k + (size_t)bh * S * 64;
  const bf16* vb = vt + (size_t)bh * 64 * S;

  const int lrow = l >> 3;
  const int clog = ((l & 7) ^ (lrow & 7)) * 8;   // pre-swizzled source chunk

  auto stage = [&](int st, int b) {
#pragma unroll
    for (int sub = 0; sub < 2; sub++) {
      const int nt = 2 * st + sub;
      GLDS16(kb + (size_t)(nt * 64 + w * 8 + lrow) * 64 + clog,
             &Ks[b][sub * 4096 + w * 512]);
      GLDS16(vb + (size_t)(w * 8 + lrow) * S + nt * 64 + clog,
             &Vs[b][sub * 4096 + w * 512]);
    }
  };

  const int swz = (q5 & 7) << 4;
  int kaddr[4], vaddr[8];
#pragma unroll
  for (int c = 0; c < 4; c++)
    kaddr[c] = q5 * 128 + ((32 * c + 16 * hi2) ^ swz);
#pragma unroll
  for (int m = 0; m < 8; m++)
    vaddr[m] = q5 * 128 + ((16 * m) ^ swz) + 8 * hi2;

  const int b_ = bh >> 4, h_ = bh & 15;
  const char* KsB = (const char*)&Ks[0][0];
  const char* VsB = (const char*)&Vs[0][0];

  const int wqbase = qt * 256 + w * 32;
  const int qrow = wqbase + q5;
  bf16x8 qf[4];   // Q^T B-operand, chunk c: d = 16c+8*hi2+(0..7); scaled
#pragma unroll
  for (int c = 0; c < 4; c++) {
    bf16x8 rq = *(const bf16x8*)&qb[(size_t)qrow * 64 + 16 * c + 8 * hi2];
    bf16x8 s_;
#pragma unroll
    for (int j2 = 0; j2 < 8; j2++)
      s_[j2] = (bf16)((float)rq[j2] * 0.18033688011112042f);
    qf[c] = s_;
  }

  f32x16 acc[2] = {};
  float l_r = 0.f;
  const int nst = 2 * qt + 2;            // steps of 128 kv
  const int qmaxw = wqbase + 31;

  stage(0, 0);
#pragma unroll 1
  for (int s = 0; s < nst; ++s) {
    if (s + 1 < nst) {
      stage(s + 1, (s + 1) & 1);
      asm volatile("s_waitcnt vmcnt(4)" ::: "memory");
    } else {
      asm volatile("s_waitcnt vmcnt(0)" ::: "memory");
    }
    __builtin_amdgcn_s_barrier();
    __builtin_amdgcn_sched_barrier(0);

    const int bo_buf = (s & 1) * 16384;
    float rs = 0.f;
#pragma unroll
    for (int sub = 0; sub < 2; sub++) {
      const int nt = 2 * s + sub;
      if (64 * nt > qmaxw) continue;     // wave-uniform causal gate
      const int bo = bo_buf + sub * 8192;
#pragma unroll
      for (int T = 0; T < 2; T++) {
        // S^T = K Q^T for half-tile T (kv 32T..32T+31 within sub)
        f32x16 sc = {};
        __builtin_amdgcn_s_setprio(1);
#pragma unroll
        for (int c = 0; c < 4; c++) {
          bf16x8 kf = *(const bf16x8*)(KsB + bo + T * 4096 + kaddr[c]);
          sc = __builtin_amdgcn_mfma_f32_32x32x16_bf16(kf, qf[c], sc, 0, 0, 0);
        }
        __builtin_amdgcn_s_setprio(0);

        if (64 * nt + 32 * T + 31 > wqbase) {   // causal mask
#pragma unroll
          for (int r = 0; r < 16; r++) {
            int kvg = 64 * nt + 32 * T + (r & 3) + 8 * (r >> 2) + 4 * hi2;
            if (kvg > qrow) sc[r] = -1e30f;
          }
        }

        // softmax (no max-subtract) + pack P for this half
        bf16x8 pa0, pa1;
#pragma unroll
        for (int r = 0; r < 8; r++) {
          float p0 = __builtin_amdgcn_exp2f(sc[r]);
          float p1 = __builtin_amdgcn_exp2f(sc[8 + r]);
          rs += p0 + p1;
          pa0[r] = (bf16)p0;
          pa1[r] = (bf16)p1;
        }

        // O += P'V for this half
        __builtin_amdgcn_s_setprio(1);
#pragma unroll
        for (int dt = 0; dt < 2; dt++) {
          bf16x4 v0 = *(const bf16x4*)(VsB + bo + dt * 4096 + vaddr[4 * T]);
          bf16x4 v1 = *(const bf16x4*)(VsB + bo + dt * 4096 + vaddr[4 * T + 1]);
          bf16x8 bv;
#pragma unroll
          for (int j2 = 0; j2 < 4; j2++) { bv[j2] = v0[j2]; bv[4 + j2] = v1[j2]; }
          acc[dt] = __builtin_amdgcn_mfma_f32_32x32x16_bf16(pa0, bv, acc[dt], 0, 0, 0);
          v0 = *(const bf16x4*)(VsB + bo + dt * 4096 + vaddr[4 * T + 2]);
          v1 = *(const bf16x4*)(VsB + bo + dt * 4096 + vaddr[4 * T + 3]);
#pragma unroll
          for (int j2 = 0; j2 < 4; j2++) { bv[j2] = v0[j2]; bv[4 + j2] = v1[j2]; }
          acc[dt] = __builtin_amdgcn_mfma_f32_32x32x16_bf16(pa1, bv, acc[dt], 0, 0, 0);
        }
        __builtin_amdgcn_s_setprio(0);
      }
    }
    rs += __shfl_xor(rs, 32);
    l_r += rs;

    asm volatile("s_waitcnt lgkmcnt(0)" ::: "memory");
    __builtin_amdgcn_sched_barrier(0);
    __builtin_amdgcn_s_barrier();
  }

  // epilogue: O row = qt*256 + w*32 + rmap(r,hi2), col d = 32dt + q5
  float linv = 1.f / l_r;
#pragma unroll
  for (int r = 0; r < 16; r++) {
    int rmap = (r & 3) + 8 * (r >> 2) + 4 * hi2;
    float li = __shfl(linv, rmap);
    int rowq = wqbase + rmap;
    size_t rb = ((size_t)(b_ * S + rowq) << 10) + h_ * 64 + q5;
#pragma unroll
    for (int dt = 0; dt < 2; dt++)
      att[rb + 32 * dt] = (bf16)(acc[dt][r] * li);
  }
}

extern "C" void kernel_launch(void* const* d_in, const int* in_sizes, int n_in,
                              void* d_out, int out_size, void* d_ws, size_t ws_size,
                              hipStream_t stream) {
  const float* x  = (const float*)d_in[0];
  const int* tp   = (const int*)d_in[1];
  const float* wq = (const float*)d_in[2];
  const float* wk = (const float*)d_in[3];
  const float* wv = (const float*)d_in[4];
  const float* wo = (const float*)d_in[5];
  float* out = (float*)d_out;

  char* ws = (char*)d_ws;
  const size_t TEN = 16777216;  // 8192*1024*2 bytes
  bf16* x_bf    = (bf16*)(ws);
  bf16* q_bf    = (bf16*)(ws + TEN);
  bf16* k_bf    = (bf16*)(ws + 2 * TEN);
  bf16* v_bf    = (bf16*)(ws + 3 * TEN);
  bf16* wqkv_bf = (bf16*)(ws + 4 * TEN);          // 3072x1024 = 6MB
  bf16* wo_bf   = wqkv_bf + 3 * 1048576;          // 2MB
  bf16* tabc    = wo_bf + 1048576;                // 512KB (8192x32 bf16)
  bf16* tabs    = tabc + 262144;                  // 512KB
  bf16* att_bf  = x_bf;   // alias: x_bf dead after QKV projection

  cvt_all<<<7168, 256, 0, stream>>>(x, wq, wk, wv, wo, tp, x_bf, wqkv_bf,
                                    wo_bf, tabc, tabs);

  dim3 gq(64, 24);
  gemm_k<0><<<gq, 256, 0, stream>>>(x_bf, wqkv_bf, tabc, tabs, q_bf, k_bf,
                                    v_bf, nullptr);

  attn_k<<<512, 512, 0, stream>>>(q_bf, k_bf, v_bf, att_bf);

  dim3 go(64, 8);
  gemm_k<2><<<go, 256, 0, stream>>>(att_bf, wo_bf, nullptr, nullptr, nullptr,
                                    nullptr, nullptr, out);
}

// Round 17
// 148.117 us; speedup vs baseline: 1.4154x; 1.4154x over previous
//
#include <hip/hip_runtime.h>
#include <hip/hip_bf16.h>
#include <stdint.h>

typedef __bf16 bf16;
typedef __bf16 bf16x4 __attribute__((ext_vector_type(4)));
typedef __bf16 bf16x8 __attribute__((ext_vector_type(8)));
typedef float f32x4 __attribute__((ext_vector_type(4)));
typedef float f32x16 __attribute__((ext_vector_type(16)));

#define GLDS16(g, l) __builtin_amdgcn_global_load_lds( \
    (const __attribute__((address_space(1))) void*)(g), \
    (__attribute__((address_space(3))) void*)(l), 16, 0, 0)

static constexpr int S = 2048;

// ---- fused f32->bf16 convert (x + 4 weights) + RoPE cos/sin table build ----
__global__ __launch_bounds__(256) void cvt_all(const float* __restrict__ x,
                                               const float* __restrict__ wq,
                                               const float* __restrict__ wk,
                                               const float* __restrict__ wv,
                                               const float* __restrict__ wo,
                                               const int* __restrict__ tp,
                                               bf16* __restrict__ xb,
                                               bf16* __restrict__ wqkvb,
                                               bf16* __restrict__ wob,
                                               bf16* __restrict__ tabc,
                                               bf16* __restrict__ tabs) {
  const int bid = blockIdx.x;
  if (bid >= 6144) {   // RoPE table: 8192 rows x 32 pairs
    int idx = (bid - 6144) * 256 + threadIdx.x;   // 0..262143
    int row = idx >> 5, pp = idx & 31;
    float p = (float)tp[row];
    float ang = p * exp2f((float)pp * -0.4152410118609203f);
    float sn, cs;
    sincosf(ang, &sn, &cs);
    tabc[idx] = (bf16)cs;
    tabs[idx] = (bf16)sn;
    return;
  }
  const float* src;
  bf16* dst;
  int i;
  if (bid < 4096) {            // x: 1,048,576 groups of 8
    src = x; dst = xb; i = bid * 256 + threadIdx.x;
  } else {                     // weights: 131,072 groups each
    int w = (bid - 4096) >> 9;
    i = ((bid - 4096) & 511) * 256 + threadIdx.x;
    src = (w == 0) ? wq : (w == 1) ? wk : (w == 2) ? wv : wo;
    dst = (w == 3) ? wob : wqkvb + (size_t)w * 1048576;
  }
  const float4* p = (const float4*)src + (size_t)i * 2;
  float4 a = p[0], b = p[1];
  bf16x8 o;
  o[0] = (bf16)a.x; o[1] = (bf16)a.y; o[2] = (bf16)a.z; o[3] = (bf16)a.w;
  o[4] = (bf16)b.x; o[5] = (bf16)b.y; o[6] = (bf16)b.z; o[7] = (bf16)b.w;
  *((bf16x8*)dst + i) = o;
}

// ---------------- NT GEMM, 128x128 tile, BK=32, 3-ring, ONE barrier/step ----
// (r15-proven) stage issued AFTER the entry barrier; WAR: ovr at step t was
// read at t-1 and those reads are lgkm-complete before each wave passes
// barrier t; RAW: tile t staged at t-2, vmcnt(4) leaves only tile t+1's
// loads in flight. One rendezvous per step, no lgkm drain.
// chunk^((row>>1)&3) swizzle pre-applied to the global source. 2D grid
// natural dispatch: XCD = bm%8 -> L2 co-location.
// MODE 0 (QKV, grid 64x24): bn<8 q, bn<16 k (table-RoPE, LDS-bounce stores);
//   bn>=16 v = W.x^T -> [b,h,dd,s] coalesced rows.
// MODE 2 (wo, grid 64x8): f32 direct stores to [m][1024].
template <int MODE>
__global__ __launch_bounds__(256, 3) void gemm_k(const bf16* __restrict__ xA,
                                                 const bf16* __restrict__ wB,
                                                 const bf16* __restrict__ tabc,
                                                 const bf16* __restrict__ tabs,
                                                 bf16* __restrict__ oq,
                                                 bf16* __restrict__ ok,
                                                 bf16* __restrict__ ov,
                                                 float* __restrict__ outf) {
  constexpr int K = 1024;
  __shared__ __align__(16) char lds[49152];
  const int t = threadIdx.x, l = t & 63, wid = t >> 6;
  const int wm = wid >> 1, wn = wid & 1;
  const int bm = blockIdx.x, bn = blockIdx.y;

  // ---- block decode
  int sel, tA, tB;
  const bf16 *Ap, *Bp;
  if (MODE == 0) {
    if (bn < 16) {
      sel = bn >> 3;                                 // 0=q, 1=k
      tA = bm;                                       // s-tile 0..63
      tB = bn & 7;                                   // col-tile 0..7
      Ap = xA + (size_t)tA * 128 * K;
      Bp = wB + (size_t)(sel * 1024 + tB * 128) * K;
    } else {
      sel = 2;
      tA = bn - 16;                                  // dd-tile 0..7
      tB = bm;                                       // s-tile 0..63
      Ap = wB + (size_t)(2048 + tA * 128) * K;       // A = wv rows (dd)
      Bp = xA + (size_t)tB * 128 * K;                // B = x rows (s)
    }
  } else {
    sel = 3;
    tA = bm; tB = bn;
    Ap = xA + (size_t)tA * 128 * K;
    Bp = wB + (size_t)tB * 128 * K;
  }

  // ---- staging: 4 GLDS16/wave/step; lane l -> row l>>2, chunk l&3 (16B)
  const int lrow = l >> 2;
  const int csrc = ((l & 3) ^ ((l >> 3) & 3)) * 8;
  const bf16* aS = Ap + (size_t)(wid * 32 + lrow) * K + csrc;
  const bf16* bS = Bp + (size_t)(wid * 32 + lrow) * K + csrc;

  auto stage = [&](int kt, char* base) {
    GLDS16(aS + kt, base + (wid * 32) * 64);
    GLDS16(aS + (size_t)16 * K + kt, base + (wid * 32 + 16) * 64);
    GLDS16(bS + kt, base + 8192 + (wid * 32) * 64);
    GLDS16(bS + (size_t)16 * K + kt, base + 8192 + (wid * 32 + 16) * 64);
  };

  // ---- loop-invariant LDS read offsets
  int offA[4], offB[4];
#pragma unroll
  for (int f = 0; f < 4; f++) {
    int ra = wm * 64 + f * 16 + (l & 15);
    offA[f] = ra * 64 + (((l >> 4) ^ ((ra >> 1) & 3)) * 16);
    int rb = wn * 64 + f * 16 + (l & 15);
    offB[f] = 8192 + rb * 64 + (((l >> 4) ^ ((rb >> 1) & 3)) * 16);
  }

  f32x4 acc[4][4] = {};

  char* cur = lds;
  char* nxt = lds + 16384;
  char* ovr = lds + 32768;
  stage(0, cur);
  stage(32, nxt);
#pragma unroll 1
  for (int t_ = 0; t_ < 32; ++t_) {
    if (t_ < 31) {
      asm volatile("s_waitcnt vmcnt(4)" ::: "memory");
    } else {
      asm volatile("s_waitcnt vmcnt(0)" ::: "memory");
    }
    __builtin_amdgcn_s_barrier();
    __builtin_amdgcn_sched_barrier(0);
    // stage AFTER the barrier: all waves' step-(t-1) reads of ovr are done.
    if (t_ + 2 < 32) stage((t_ + 2) * 32, ovr);

    bf16x8 af[4], bg[4];
#pragma unroll
    for (int f = 0; f < 4; f++) {
      af[f] = *(const bf16x8*)(cur + offA[f]);
      bg[f] = *(const bf16x8*)(cur + offB[f]);
    }
    __builtin_amdgcn_s_setprio(1);
#pragma unroll
    for (int mi = 0; mi < 4; mi++)
#pragma unroll
      for (int ni = 0; ni < 4; ni++)
        acc[mi][ni] = __builtin_amdgcn_mfma_f32_16x16x32_bf16(
            af[mi], bg[ni], acc[mi][ni], 0, 0, 0);
    __builtin_amdgcn_s_setprio(0);
    char* tmp = cur; cur = nxt; nxt = ovr; ovr = tmp;
  }

  if (MODE == 2) {   // wo: direct f32 stores (64 B segments, full lines)
    const int rbase = tA * 128 + wm * 64 + (l >> 4) * 4;
    const int cbase = tB * 128 + wn * 64 + (l & 15);
#pragma unroll
    for (int mi = 0; mi < 4; mi++)
#pragma unroll
      for (int ni = 0; ni < 4; ni++)
#pragma unroll
        for (int r = 0; r < 4; r++)
          outf[(size_t)(rbase + mi * 16 + r) * 1024 + cbase + ni * 16] =
              acc[mi][ni][r];
    return;
  }

  // ---- 2-pass half-tile epilogue via 64x272B overlay (ring is dead)
  __syncthreads();
#pragma unroll 1
  for (int pass = 0; pass < 2; ++pass) {
    if (wm == pass) {   // waves owning rows [pass*64, pass*64+64)
#pragma unroll
      for (int mi = 0; mi < 4; mi++)
#pragma unroll
        for (int ni = 0; ni < 4; ni++)
#pragma unroll
          for (int r = 0; r < 4; r++) {
            int rloc = mi * 16 + (l >> 4) * 4 + r;       // 0..63
            int col = wn * 64 + ni * 16 + (l & 15);      // 0..127
            *(bf16*)(lds + rloc * 272 + col * 2) = (bf16)acc[mi][ni][r];
          }
    }
    __syncthreads();
#pragma unroll 2
    for (int i = 0; i < 4; ++i) {
      const int id = t + 256 * i;
      const int rloc = id >> 4, ch = id & 15;
      bf16x8 v8 = *(const bf16x8*)(lds + rloc * 272 + ch * 16);
      const int row = pass * 64 + rloc;
      if (sel < 2) {
        const int m = tA * 128 + row;
        const int g = ch & 7;
        bf16x4 tc = *(const bf16x4*)(tabc + m * 32 + g * 4);
        bf16x4 tsn = *(const bf16x4*)(tabs + m * 32 + g * 4);
        bf16x8 o;
#pragma unroll
        for (int j = 0; j < 4; j++) {
          float cs = (float)tc[j], sn = (float)tsn[j];
          float e = (float)v8[2 * j], od = (float)v8[2 * j + 1];
          o[2 * j]     = (bf16)(e * cs - od * sn);
          o[2 * j + 1] = (bf16)(e * sn + od * cs);
        }
        bf16* dst = (sel == 0) ? oq : ok;
        const int h = tB * 2 + (ch >> 3);
        size_t idx = ((size_t)((m >> 11) * 16 + h) << 17) +
                     ((size_t)(m & 2047) << 6) + g * 8;
        *(bf16x8*)(dst + idx) = o;
      } else {
        const int dd = tA * 128 + row;
        const int h = dd >> 6;
        const int s0 = tB * 128 + ch * 8;
        size_t idx = ((size_t)((s0 >> 11) * 16 + h) << 17) +
                     ((size_t)(dd & 63) << 11) + (s0 & 2047);
        *(bf16x8*)(ov + idx) = v8;
      }
    }
    __syncthreads();
  }
}

// ---------------- causal flash attention, KVBLK=128, ONE barrier/step -------
// r12 body + r15-proven one-barrier transform: per step
//   vmcnt(0) [own tile-s loads] -> barrier [all waves' tile-s landed] ->
//   stage(s+1) [WAR: buf[(s+1)&1] read at s-1; those reads lgkm-complete
//   before each wave passed barrier s] -> compute. No trailing sync.
// 512 blocks (one (bh,qt) each), 8 waves, QBLK=256, dbuf 64 KB, 2 blocks/CU.
// Swapped QK^T; sigma-permuted in-register P; no max-subtract softmax.
__global__ __launch_bounds__(512, 4) void attn_k(const bf16* __restrict__ q,
                                                 const bf16* __restrict__ k,
                                                 const bf16* __restrict__ vt,
                                                 bf16* __restrict__ att) {
  __shared__ bf16 Ks[2][8192];   // [buf][sub*4096 + kv64 x d64], swizzled
  __shared__ bf16 Vs[2][8192];   // [buf][sub*4096 + d64 x kv64], swizzled

  const int t = threadIdx.x, l = t & 63, w = t >> 6;   // w = 0..7
  const int hi2 = l >> 5, q5 = l & 31;

  const int raw = blockIdx.x;
  const int r2 = raw & 255;
  const int wg = (r2 & 7) * 32 + (r2 >> 3);      // 4 bh per XCD, L2-local
  const int bh = ((raw < 256) ? 0 : 32) + (wg >> 3);
  const int qt = (raw < 256) ? (wg & 7) : 7 - (wg & 7);

  const bf16* qb = q + (size_t)bh * S * 64;
  const bf16* kb = k + (size_t)bh * S * 64;
  const bf16* vb = vt + (size_t)bh * 64 * S;

  const int lrow = l >> 3;
  const int clog = ((l & 7) ^ (lrow & 7)) * 8;   // pre-swizzled source chunk

  auto stage = [&](int st, int b) {
#pragma unroll
    for (int sub = 0; sub < 2; sub++) {
      const int nt = 2 * st + sub;
      GLDS16(kb + (size_t)(nt * 64 + w * 8 + lrow) * 64 + clog,
             &Ks[b][sub * 4096 + w * 512]);
      GLDS16(vb + (size_t)(w * 8 + lrow) * S + nt * 64 + clog,
             &Vs[b][sub * 4096 + w * 512]);
    }
  };

  const int swz = (q5 & 7) << 4;
  int kaddr[4], vaddr[8];
#pragma unroll
  for (int c = 0; c < 4; c++)
    kaddr[c] = q5 * 128 + ((32 * c + 16 * hi2) ^ swz);
#pragma unroll
  for (int m = 0; m < 8; m++)
    vaddr[m] = q5 * 128 + ((16 * m) ^ swz) + 8 * hi2;

  const int b_ = bh >> 4, h_ = bh & 15;
  const char* KsB = (const char*)&Ks[0][0];
  const char* VsB = (const char*)&Vs[0][0];

  const int wqbase = qt * 256 + w * 32;
  const int qrow = wqbase + q5;
  bf16x8 qf[4];   // Q^T B-operand, chunk c: d = 16c+8*hi2+(0..7); scaled
#pragma unroll
  for (int c = 0; c < 4; c++) {
    bf16x8 rq = *(const bf16x8*)&qb[(size_t)qrow * 64 + 16 * c + 8 * hi2];
    bf16x8 s_;
#pragma unroll
    for (int j2 = 0; j2 < 8; j2++)
      s_[j2] = (bf16)((float)rq[j2] * 0.18033688011112042f);
    qf[c] = s_;
  }

  f32x16 acc[2] = {};
  float l_r = 0.f;
  const int nst = 2 * qt + 2;            // steps of 128 kv
  const int qmaxw = wqbase + 31;

  stage(0, 0);
#pragma unroll 1
  for (int s = 0; s < nst; ++s) {
    asm volatile("s_waitcnt vmcnt(0)" ::: "memory");   // own tile-s loads
    __builtin_amdgcn_s_barrier();                      // all waves' landed
    __builtin_amdgcn_sched_barrier(0);
    if (s + 1 < nst) stage(s + 1, (s + 1) & 1);        // after barrier (WAR)

    const int bo_buf = (s & 1) * 16384;
    float rs = 0.f;
#pragma unroll
    for (int sub = 0; sub < 2; sub++) {
      const int nt = 2 * s + sub;
      if (64 * nt > qmaxw) continue;     // wave-uniform causal gate
      const int bo = bo_buf + sub * 8192;
#pragma unroll
      for (int T = 0; T < 2; T++) {
        // S^T = K Q^T for half-tile T (kv 32T..32T+31 within sub)
        f32x16 sc = {};
        __builtin_amdgcn_s_setprio(1);
#pragma unroll
        for (int c = 0; c < 4; c++) {
          bf16x8 kf = *(const bf16x8*)(KsB + bo + T * 4096 + kaddr[c]);
          sc = __builtin_amdgcn_mfma_f32_32x32x16_bf16(kf, qf[c], sc, 0, 0, 0);
        }
        __builtin_amdgcn_s_setprio(0);

        if (64 * nt + 32 * T + 31 > wqbase) {   // causal mask
#pragma unroll
          for (int r = 0; r < 16; r++) {
            int kvg = 64 * nt + 32 * T + (r & 3) + 8 * (r >> 2) + 4 * hi2;
            if (kvg > qrow) sc[r] = -1e30f;
          }
        }

        // softmax (no max-subtract) + pack P for this half
        bf16x8 pa0, pa1;
#pragma unroll
        for (int r = 0; r < 8; r++) {
          float p0 = __builtin_amdgcn_exp2f(sc[r]);
          float p1 = __builtin_amdgcn_exp2f(sc[8 + r]);
          rs += p0 + p1;
          pa0[r] = (bf16)p0;
          pa1[r] = (bf16)p1;
        }

        // O += P'V for this half
        __builtin_amdgcn_s_setprio(1);
#pragma unroll
        for (int dt = 0; dt < 2; dt++) {
          bf16x4 v0 = *(const bf16x4*)(VsB + bo + dt * 4096 + vaddr[4 * T]);
          bf16x4 v1 = *(const bf16x4*)(VsB + bo + dt * 4096 + vaddr[4 * T + 1]);
          bf16x8 bv;
#pragma unroll
          for (int j2 = 0; j2 < 4; j2++) { bv[j2] = v0[j2]; bv[4 + j2] = v1[j2]; }
          acc[dt] = __builtin_amdgcn_mfma_f32_32x32x16_bf16(pa0, bv, acc[dt], 0, 0, 0);
          v0 = *(const bf16x4*)(VsB + bo + dt * 4096 + vaddr[4 * T + 2]);
          v1 = *(const bf16x4*)(VsB + bo + dt * 4096 + vaddr[4 * T + 3]);
#pragma unroll
          for (int j2 = 0; j2 < 4; j2++) { bv[j2] = v0[j2]; bv[4 + j2] = v1[j2]; }
          acc[dt] = __builtin_amdgcn_mfma_f32_32x32x16_bf16(pa1, bv, acc[dt], 0, 0, 0);
        }
        __builtin_amdgcn_s_setprio(0);
      }
    }
    rs += __shfl_xor(rs, 32);
    l_r += rs;
  }

  // epilogue: O row = qt*256 + w*32 + rmap(r,hi2), col d = 32dt + q5
  float linv = 1.f / l_r;
#pragma unroll
  for (int r = 0; r < 16; r++) {
    int rmap = (r & 3) + 8 * (r >> 2) + 4 * hi2;
    float li = __shfl(linv, rmap);
    int rowq = wqbase + rmap;
    size_t rb = ((size_t)(b_ * S + rowq) << 10) + h_ * 64 + q5;
#pragma unroll
    for (int dt = 0; dt < 2; dt++)
      att[rb + 32 * dt] = (bf16)(acc[dt][r] * li);
  }
}

extern "C" void kernel_launch(void* const* d_in, const int* in_sizes, int n_in,
                              void* d_out, int out_size, void* d_ws, size_t ws_size,
                              hipStream_t stream) {
  const float* x  = (const float*)d_in[0];
  const int* tp   = (const int*)d_in[1];
  const float* wq = (const float*)d_in[2];
  const float* wk = (const float*)d_in[3];
  const float* wv = (const float*)d_in[4];
  const float* wo = (const float*)d_in[5];
  float* out = (float*)d_out;

  char* ws = (char*)d_ws;
  const size_t TEN = 16777216;  // 8192*1024*2 bytes
  bf16* x_bf    = (bf16*)(ws);
  bf16* q_bf    = (bf16*)(ws + TEN);
  bf16* k_bf    = (bf16*)(ws + 2 * TEN);
  bf16* v_bf    = (bf16*)(ws + 3 * TEN);
  bf16* wqkv_bf = (bf16*)(ws + 4 * TEN);          // 3072x1024 = 6MB
  bf16* wo_bf   = wqkv_bf + 3 * 1048576;          // 2MB
  bf16* tabc    = wo_bf + 1048576;                // 512KB (8192x32 bf16)
  bf16* tabs    = tabc + 262144;                  // 512KB
  bf16* att_bf  = x_bf;   // alias: x_bf dead after QKV projection

  cvt_all<<<7168, 256, 0, stream>>>(x, wq, wk, wv, wo, tp, x_bf, wqkv_bf,
                                    wo_bf, tabc, tabs);

  dim3 gq(64, 24);
  gemm_k<0><<<gq, 256, 0, stream>>>(x_bf, wqkv_bf, tabc, tabs, q_bf, k_bf,
                                    v_bf, nullptr);

  attn_k<<<512, 512, 0, stream>>>(q_bf, k_bf, v_bf, att_bf);

  dim3 go(64, 8);
  gemm_k<2><<<go, 256, 0, stream>>>(att_bf, wo_bf, nullptr, nullptr, nullptr,
                                    nullptr, nullptr, out);
}